// Round 1
// baseline (62.213 us; speedup 1.0000x reference)
//
#include <hip/hip_runtime.h>

// Problem constants (from reference):
//   B=64, C=3, S=384, P=32, R=169
//   out0: patches (B*R, C, P, P) f32   -> 33,226,752 elements
//   out1: pos     (B, R, 2)      f32   -> 21,632 elements (flat after patches)
#define Bn 64
#define Cn 3
#define Sn 384
#define Pn 32
#define Rn 169
#define TILE_W 33                       // 33x33 window always suffices (scale<1)
#define TILE_ELEMS (TILE_W * TILE_W)    // 1089
#define PATCH_ELEMS (Cn * Pn * Pn)      // 3072
#define POS_OFFSET ((size_t)Bn * Rn * Cn * Pn * Pn)  // 33226752

__global__ __launch_bounds__(256) void patch_kernel(
    const float* __restrict__ x,        // (B, C, S, S)
    const int*   __restrict__ crop_top, // (B, R)  -> drives COLUMN axis (i)
    const int*   __restrict__ crop_left,// (B, R)  -> drives ROW axis (j)
    float*       __restrict__ out)
{
    const int pr = blockIdx.x;          // b*R + r
    const int b  = pr / Rn;
    const int t  = threadIdx.x;

    __shared__ float tile[Cn][TILE_ELEMS];
    __shared__ float s_wx[Pn], s_wy[Pn];
    __shared__ int   s_x0[Pn], s_y0[Pn];

    const float scale = 383.0f / 384.0f;   // (S-1)/S, f32 — matches jnp weak-type cast

    const int ct = crop_top[pr];        // uniform per block -> scalar load
    const int cl = crop_left[pr];
    const int col_base = (int)floorf((float)ct * scale);
    const int row_base = (int)floorf((float)cl * scale);
    // Since crop <= S-P = 352: base <= 351, base+32 <= 383 -> window always in-bounds.

    // Per-patch interpolation tables (exact reference arithmetic, f32).
    if (t < Pn) {
        float cx = ((float)t + (float)ct) * scale;   // column position (i axis)
        float fx = floorf(cx);
        s_x0[t] = (int)fx - col_base;                // in [0,31]; +1 stays <= 32
        s_wx[t] = cx - fx;
        float cy = ((float)t + (float)cl) * scale;   // row position (j axis)
        float fy = floorf(cy);
        s_y0[t] = (int)fy - row_base;
        s_wy[t] = cy - fy;
    }

    // Stage x[b, c, row_base:+33, col_base:+33] for all 3 channels into LDS.
    // 3*1089 = 3267 elements, 256 threads -> 13 strided iterations.
    const float* xb = x + (size_t)b * (Cn * Sn * Sn);
    #pragma unroll
    for (int k = 0; k < 13; ++k) {
        int idx = t + k * 256;
        if (idx < Cn * TILE_ELEMS) {
            int c   = idx / TILE_ELEMS;
            int rem = idx - c * TILE_ELEMS;
            int rr  = rem / TILE_W;
            int cc  = rem - rr * TILE_W;
            tile[c][rem] = xb[c * (Sn * Sn) + (row_base + rr) * Sn + (col_base + cc)];
        }
    }
    __syncthreads();

    // Each thread: j = t&31 (output fast axis = x ROW axis), i walks 8..8+ per step.
    // Per 256-thread step the block writes 256 contiguous floats (coalesced).
    float* outp = out + (size_t)pr * PATCH_ELEMS;
    const int   j  = t & 31;
    const int   i0 = t >> 5;            // 0..7
    const float wy = s_wy[j];
    const int   y0 = s_y0[j];
    const float one_wy = 1.0f - wy;

    #pragma unroll
    for (int c = 0; c < Cn; ++c) {
        const float* T = tile[c];
        #pragma unroll
        for (int s = 0; s < 4; ++s) {
            int   i  = s * 8 + i0;
            float wx = s_wx[i];
            int   x0 = s_x0[i];
            // LDS: stride 33 -> bank (y0 + x0) % 32; 32 lanes have ~distinct
            // consecutive y0 -> conflict-free.
            float v00 = T[y0 * TILE_W + x0];
            float v01 = T[y0 * TILE_W + x0 + 1];
            float v10 = T[y0 * TILE_W + TILE_W + x0];
            float v11 = T[y0 * TILE_W + TILE_W + x0 + 1];
            float one_wx = 1.0f - wx;
            float val = one_wy * one_wx * v00 + one_wy * wx * v01
                      + wy     * one_wx * v10 + wy     * wx * v11;
            outp[(c * Pn + i) * Pn + j] = val;
        }
    }

    // pos output: pos[b,r,0] = crop_top, pos[b,r,1] = crop_left
    if (t < 2) {
        out[POS_OFFSET + (size_t)pr * 2 + t] = (t == 0) ? (float)ct : (float)cl;
    }
}

extern "C" void kernel_launch(void* const* d_in, const int* in_sizes, int n_in,
                              void* d_out, int out_size, void* d_ws, size_t ws_size,
                              hipStream_t stream) {
    const float* x         = (const float*)d_in[0];
    const int*   crop_top  = (const int*)d_in[1];
    const int*   crop_left = (const int*)d_in[2];
    float*       out       = (float*)d_out;

    dim3 grid(Bn * Rn);   // 10816 blocks, one per patch
    dim3 block(256);
    patch_kernel<<<grid, block, 0, stream>>>(x, crop_top, crop_left, out);
}

// Round 2
// 41.264 us; speedup vs baseline: 1.5077x; 1.5077x over previous
//
#include <hip/hip_runtime.h>

// Problem: B=64, C=3, S=384, P=32, R=169
//   out0: patches (B*R, C, P, P) f32 -> 33,226,752 elems
//   out1: pos     (B, R, 2)      f32 -> 21,632 elems (flat after patches)
//
// out[b,r,c,i,j] = bilinear sample of x[b,c,·,·] at
//   row = (j + crop_left[b,r]) * scale   (j = output fast axis)
//   col = (i + crop_top [b,r]) * scale
// scale = 383/384 < 1  =>  33x33 window starting at floor(crop*scale) always
// suffices and stays in-bounds (crop <= 352 -> base+32 <= 383). Verified R1.
#define Bn 64
#define Cn 3
#define Sn 384
#define Pn 32
#define Rn 169
#define TILE_W 33
#define TILE_ELEMS (TILE_W * TILE_W)                 // 1089
#define PATCH_ELEMS (Cn * Pn * Pn)                   // 3072
#define POS_OFFSET ((size_t)Bn * Rn * Cn * Pn * Pn)  // 33226752
#define NBLK (Bn * Rn)                               // 10816 = 8 * 1352

typedef float f4 __attribute__((ext_vector_type(4)));
typedef f4 uf4 __attribute__((aligned(4)));          // 4B-aligned float4 load

__global__ __launch_bounds__(512) void patch_kernel(
    const float* __restrict__ x,         // (B, C, S, S)
    const int*   __restrict__ crop_top,  // (B, R) -> column axis (i)
    const int*   __restrict__ crop_left, // (B, R) -> row axis (j)
    float*       __restrict__ out)
{
    // XCD-bijective swizzle: 10816 % 8 == 0; each XCD gets 1352 contiguous
    // patches = exactly 8 whole images -> L2-resident sliding window.
    const int bid = blockIdx.x;
    const int pr  = (bid & 7) * (NBLK / 8) + (bid >> 3);
    const int b   = pr / Rn;
    const int t   = threadIdx.x;

    // Transposed tile: T[c][col][row], row (j axis) is the fast axis.
    // => v00/v10 and v01/v11 are adjacent dwords (ds_read2_b32), and the
    //    32 j-lanes read consecutive addresses (conflict-free, any stride).
    __shared__ float T[Cn * TILE_ELEMS];  // 13068 B

    const float scale = 383.0f / 384.0f;  // same expression as R1 (passed)

    const int ct = crop_top[pr];          // block-uniform -> scalar regs
    const int cl = crop_left[pr];
    const int col_base = (int)floorf((float)ct * scale);
    const int row_base = (int)floorf((float)cl * scale);

    const float* xb = x + (size_t)b * (Cn * Sn * Sn);

    // ---- Stage: 99 image rows x (8 float4 + 1 scalar) = 891 tasks ----
    // Global reads: contiguous along image rows (coalesced, vectorized).
    // LDS writes: transposed scatter -> pairs at +0/+33 dwords (ds_write2).
    #pragma unroll
    for (int k = 0; k < 2; ++k) {
        int idx = t + k * 512;
        if (idx < 99 * 9) {
            int row = idx / 9;                       // 0..98  (magic mul)
            int q   = idx - row * 9;                 // 0..8
            int c   = (row >= 66) ? 2 : ((row >= 33) ? 1 : 0);
            int rr  = row - c * 33;                  // image row within window
            const float* gp = xb + c * (Sn * Sn) + (row_base + rr) * Sn + col_base;
            if (q < 8) {
                f4 g = *(const uf4*)(gp + 4 * q);    // dword-aligned dwordx4
                int a = c * TILE_ELEMS + (4 * q) * TILE_W + rr;
                T[a]           = g.x;                // cols 4q..4q+3, row rr
                T[a + TILE_W]  = g.y;                // -> 2x ds_write2_b32
                T[a + 2*TILE_W] = g.z;
                T[a + 3*TILE_W] = g.w;
            } else {
                T[c * TILE_ELEMS + 32 * TILE_W + rr] = gp[32];  // col 32 tail
            }
        }
    }
    __syncthreads();

    // ---- Compute: thread owns (j = t&31, i0 = t>>5); 2 i-steps x 3 ch ----
    const int j  = t & 31;
    const int i0 = t >> 5;                 // 0..15
    float cy = ((float)j + (float)cl) * scale;
    float fy = floorf(cy);
    float wy = cy - fy;
    int   y0 = (int)fy - row_base;         // in [0,31]
    float one_wy = 1.0f - wy;

    float* outp = out + (size_t)pr * PATCH_ELEMS + j;

    #pragma unroll
    for (int s = 0; s < 2; ++s) {
        int   i  = i0 + 16 * s;
        float cx = ((float)i + (float)ct) * scale;
        float fx = floorf(cx);
        float wx = cx - fx;
        int   x0 = (int)fx - col_base;     // in [0,31]
        float one_wx = 1.0f - wx;
        float w00 = one_wy * one_wx;
        float w01 = one_wy * wx;
        float w10 = wy * one_wx;
        float w11 = wy * wx;
        int a = x0 * TILE_W + y0;          // lanes: consecutive y0 -> no conflicts
        #pragma unroll
        for (int c = 0; c < Cn; ++c) {
            const float* Tc = T + c * TILE_ELEMS;
            float v00 = Tc[a];             // (y0,   x0)
            float v10 = Tc[a + 1];         // (y0+1, x0)    } ds_read2_b32
            float v01 = Tc[a + TILE_W];    // (y0,   x0+1)
            float v11 = Tc[a + TILE_W + 1];// (y0+1, x0+1)  } ds_read2_b32
            float val = w00 * v00 + w01 * v01 + w10 * v10 + w11 * v11;
            outp[c * (Pn * Pn) + i * Pn] = val;   // 256B contiguous per wave
        }
    }

    // pos[b,r,0] = crop_top, pos[b,r,1] = crop_left
    if (t < 2) {
        out[POS_OFFSET + (size_t)pr * 2 + t] = (t == 0) ? (float)ct : (float)cl;
    }
}

extern "C" void kernel_launch(void* const* d_in, const int* in_sizes, int n_in,
                              void* d_out, int out_size, void* d_ws, size_t ws_size,
                              hipStream_t stream) {
    const float* x         = (const float*)d_in[0];
    const int*   crop_top  = (const int*)d_in[1];
    const int*   crop_left = (const int*)d_in[2];
    float*       out       = (float*)d_out;

    patch_kernel<<<dim3(NBLK), dim3(512), 0, stream>>>(x, crop_top, crop_left, out);
}

// Round 3
// 39.855 us; speedup vs baseline: 1.5610x; 1.0354x over previous
//
#include <hip/hip_runtime.h>

// Problem: B=64, C=3, S=384, P=32, R=169
//   out0: patches (B*R, C, P, P) f32 -> 33,226,752 elems
//   out1: pos     (B, R, 2)      f32 -> 21,632 elems (flat after patches)
//
// out[b,r,c,i,j] = bilinear sample of x[b,c,·,·] at
//   row = (j + crop_left[b,r]) * scale   (j = output fast axis)
//   col = (i + crop_top [b,r]) * scale
// scale = 383/384 < 1. Verified R1/R2: 33x33 window at floor(crop*scale)
// suffices and is always in-bounds; clamp never binds.
//
// R3 changes (vs R2, 41.3us):
//  - staging loads 16B-aligned: window starts at (col_base & ~3), 36 cols
//    -> every quad is ONE global_load_dwordx4 (R2's align(4) f4 split into
//       4 scalar dwords -> VALU/VMEM bloat, VALUBusy 24.7%)
//  - thread owns a j-pair -> dwordx2 output stores (6 -> 3 store instrs)
//  - nontemporal output stores (stream-once; keep x resident in L2/L3)
#define Bn 64
#define Cn 3
#define Sn 384
#define Pn 32
#define Rn 169
#define TCOLS 36                       // 33 needed + <=3 alignment slack
#define TROWS 33
#define PLANE (TCOLS * TROWS)          // 1188
#define PATCH_ELEMS (Cn * Pn * Pn)     // 3072
#define POS_OFFSET ((size_t)Bn * Rn * Cn * Pn * Pn)  // 33226752
#define NBLK (Bn * Rn)                 // 10816 = 8 * 1352

typedef float f4 __attribute__((ext_vector_type(4)));
typedef float f2 __attribute__((ext_vector_type(2)));

__global__ __launch_bounds__(512) void patch_kernel(
    const float* __restrict__ x,         // (B, C, S, S)
    const int*   __restrict__ crop_top,  // (B, R) -> column axis (i)
    const int*   __restrict__ crop_left, // (B, R) -> row axis (j)
    float*       __restrict__ out)
{
    // XCD-bijective swizzle: 10816 % 8 == 0; consecutive pr share one image
    // for 169 blocks -> image (1.77 MB) L2-resident per XCD.
    const int bid = blockIdx.x;
    const int pr  = (bid & 7) * (NBLK / 8) + (bid >> 3);
    const int b   = pr / Rn;
    const int t   = threadIdx.x;

    // Transposed tile: T[c][col][row] (row = j axis = fast). Reads: lanes
    // scan consecutive rows, stride 1 dword -> conflict-free ds_read2.
    __shared__ float T[Cn * PLANE];      // 14256 B

    const float scale = 383.0f / 384.0f;

    const int ct = crop_top[pr];         // block-uniform -> scalar regs
    const int cl = crop_left[pr];
    const int col_base = (int)floorf((float)ct * scale);
    const int row_base = (int)floorf((float)cl * scale);
    const int start    = col_base & ~3;  // 16B-aligned window start

    const float* xb = x + (size_t)b * (Cn * Sn * Sn);

    // ---- Stage: 99 rows x 9 aligned dwordx4 = 891 tasks over 512 thr ----
    #pragma unroll
    for (int k = 0; k < 2; ++k) {
        int idx = t + k * 512;
        if (idx < 99 * 9) {
            int row = idx / 9;                       // magic-mul
            int q4  = (idx - row * 9) << 2;          // col 0,4,...,32
            int c   = (row >= 66) ? 2 : ((row >= 33) ? 1 : 0);
            int rr  = row - c * 33;
            // 16B-aligned: x base, c*S*S, row*S, start, q4 all %4==0 (dwords)
            const f4 g = *(const f4*)(xb + c * (Sn * Sn)
                                         + (row_base + rr) * Sn + start + q4);
            int a = c * PLANE + q4 * TROWS + rr;     // transposed scatter
            T[a]             = g.x;                  // -> 2x ds_write2_b32
            T[a + TROWS]     = g.y;                  //    (offsets 0/33, 66/99)
            T[a + 2 * TROWS] = g.z;
            T[a + 3 * TROWS] = g.w;
        }
    }
    __syncthreads();

    // ---- Compute: thread owns (j2 = 2*(t&15), i = t>>4); 3 ch x j-pair ----
    const int j2 = (t & 15) << 1;
    const int i  = t >> 4;

    float cx = ((float)i + (float)ct) * scale;
    float fx = floorf(cx);
    float wx = cx - fx;
    int   x0 = (int)fx - start;          // in [0,34]; +1 <= 35 < TCOLS
    float owx = 1.0f - wx;

    float cya = ((float)j2 + (float)cl) * scale;
    float fya = floorf(cya);
    float wya = cya - fya;
    int   y0a = (int)fya - row_base;     // in [0,31]
    float owya = 1.0f - wya;

    float cyb = ((float)(j2 + 1) + (float)cl) * scale;
    float fyb = floorf(cyb);
    float wyb = cyb - fyb;
    int   y0b = (int)fyb - row_base;
    float owyb = 1.0f - wyb;

    float w00a = owya * owx, w01a = owya * wx, w10a = wya * owx, w11a = wya * wx;
    float w00b = owyb * owx, w01b = owyb * wx, w10b = wyb * owx, w11b = wyb * wx;

    int basea = x0 * TROWS + y0a;
    int baseb = x0 * TROWS + y0b;

    float* outp = out + (size_t)pr * PATCH_ELEMS + i * Pn + j2;

    #pragma unroll
    for (int c = 0; c < Cn; ++c) {
        const float* Tc = T + c * PLANE;
        float v00 = Tc[basea];               // (y0a, x0)     } ds_read2_b32
        float v01 = Tc[basea + TROWS];       // (y0a, x0+1)   }
        float v10 = Tc[basea + 1];           // (y0a+1, x0)   } ds_read2_b32
        float v11 = Tc[basea + TROWS + 1];   // (y0a+1, x0+1) }
        float va  = w00a * v00 + w01a * v01 + w10a * v10 + w11a * v11;

        float u00 = Tc[baseb];
        float u01 = Tc[baseb + TROWS];
        float u10 = Tc[baseb + 1];
        float u11 = Tc[baseb + TROWS + 1];
        float vb  = w00b * u00 + w01b * u01 + w10b * u10 + w11b * u11;

        f2 v = {va, vb};
        // wave writes 4 i-groups x 16 j-pairs = 512B contiguous, stream-once
        __builtin_nontemporal_store(v, (f2*)(outp + c * (Pn * Pn)));
    }

    // pos[b,r,0] = crop_top, pos[b,r,1] = crop_left
    if (t < 2) {
        out[POS_OFFSET + (size_t)pr * 2 + t] = (t == 0) ? (float)ct : (float)cl;
    }
}

extern "C" void kernel_launch(void* const* d_in, const int* in_sizes, int n_in,
                              void* d_out, int out_size, void* d_ws, size_t ws_size,
                              hipStream_t stream) {
    const float* x         = (const float*)d_in[0];
    const int*   crop_top  = (const int*)d_in[1];
    const int*   crop_left = (const int*)d_in[2];
    float*       out       = (float*)d_out;

    patch_kernel<<<dim3(NBLK), dim3(512), 0, stream>>>(x, crop_top, crop_left, out);
}